// Round 1
// baseline (100.322 us; speedup 1.0000x reference)
//
#include <hip/hip_runtime.h>

#define NC 6
constexpr float HIER_W = 0.2f;

__global__ __launch_bounds__(256) void hloss_main(
    const float* __restrict__ preds,
    const int*   __restrict__ targets,
    const float* __restrict__ cw,
    const float* __restrict__ pen,
    float* __restrict__ acc,
    int npairs)
{
    __shared__ float s_cw[NC];
    __shared__ float s_pen[NC * NC];
    if (threadIdx.x < NC * NC) s_pen[threadIdx.x] = pen[threadIdx.x];
    if (threadIdx.x < NC)      s_cw[threadIdx.x]  = cw[threadIdx.x];
    __syncthreads();

    float a_num = 0.f, a_den = 0.f, a_h = 0.f;

    const int stride = gridDim.x * blockDim.x;
    for (int p = blockIdx.x * blockDim.x + threadIdx.x; p < npairs; p += stride) {
        // 2 rows = 12 floats = 3 aligned float4 loads
        const float4* base = reinterpret_cast<const float4*>(preds + (size_t)p * 12);
        float4 v0 = base[0];
        float4 v1 = base[1];
        float4 v2 = base[2];
        int2 t2 = reinterpret_cast<const int2*>(targets)[p];

        float x[12] = { v0.x, v0.y, v0.z, v0.w,
                        v1.x, v1.y, v1.z, v1.w,
                        v2.x, v2.y, v2.z, v2.w };

        #pragma unroll
        for (int r = 0; r < 2; ++r) {
            const float* xr = x + r * 6;          // r compile-time after unroll
            const int t = (r == 0) ? t2.x : t2.y; // runtime, 0..5

            float m = xr[0];
            #pragma unroll
            for (int j = 1; j < NC; ++j) m = fmaxf(m, xr[j]);

            float e[NC], s = 0.f;
            #pragma unroll
            for (int j = 0; j < NC; ++j) { e[j] = __expf(xr[j] - m); s += e[j]; }
            const float inv = __frcp_rn(s);

            // x[t] via compile-time-j select chain (no runtime array index -> no scratch)
            float xt = xr[0];
            #pragma unroll
            for (int j = 1; j < NC; ++j) xt = (t == j) ? xr[j] : xt;

            const float w   = s_cw[t];
            const float nll = __logf(s) - (xt - m);
            a_num += w * nll;
            a_den += w;

            const float* pr = s_pen + t * NC;     // LDS gather, tiny
            float h = 0.f;
            #pragma unroll
            for (int j = 0; j < NC; ++j) h += (j != t) ? e[j] * pr[j] : 0.f;
            a_h += h * inv;
        }
    }

    // wave (64-lane) butterfly reduction
    #pragma unroll
    for (int off = 32; off > 0; off >>= 1) {
        a_num += __shfl_xor(a_num, off);
        a_den += __shfl_xor(a_den, off);
        a_h   += __shfl_xor(a_h,   off);
    }

    __shared__ float red[3][4];
    const int wave = threadIdx.x >> 6;
    const int lane = threadIdx.x & 63;
    if (lane == 0) { red[0][wave] = a_num; red[1][wave] = a_den; red[2][wave] = a_h; }
    __syncthreads();
    if (threadIdx.x == 0) {
        float n = 0.f, d = 0.f, h = 0.f;
        #pragma unroll
        for (int i = 0; i < 4; ++i) { n += red[0][i]; d += red[1][i]; h += red[2][i]; }
        atomicAdd(&acc[0], n);
        atomicAdd(&acc[1], d);
        atomicAdd(&acc[2], h);
    }
}

__global__ void hloss_final(const float* __restrict__ acc,
                            float* __restrict__ out, float invB)
{
    const float ce = acc[0] / acc[1];
    const float h  = acc[2] * invB;
    out[0] = ce + HIER_W * h;  // total_loss
    out[1] = ce;               // ce_loss
    out[2] = h;                // hierarchy_loss
}

extern "C" void kernel_launch(void* const* d_in, const int* in_sizes, int n_in,
                              void* d_out, int out_size, void* d_ws, size_t ws_size,
                              hipStream_t stream)
{
    const float* preds   = (const float*)d_in[0];
    const int*   targets = (const int*)  d_in[1];
    const float* cw      = (const float*)d_in[2];
    const float* pen     = (const float*)d_in[3];
    float* acc = (float*)d_ws;
    float* out = (float*)d_out;

    const int B = in_sizes[1];       // number of rows (targets count)
    const int npairs = B / 2;        // B = 4194304, even

    hipMemsetAsync(acc, 0, 3 * sizeof(float), stream);

    const int threads = 256;
    int blocks = (npairs + threads - 1) / threads;
    if (blocks > 2048) blocks = 2048;

    hipLaunchKernelGGL(hloss_main, dim3(blocks), dim3(threads), 0, stream,
                       preds, targets, cw, pen, acc, npairs);
    hipLaunchKernelGGL(hloss_final, dim3(1), dim3(1), 0, stream,
                       acc, out, 1.0f / (float)B);
}

// Round 2
// 29.135 us; speedup vs baseline: 3.4434x; 3.4434x over previous
//
#include <hip/hip_runtime.h>

#define NC 6
constexpr float HIER_W = 0.2f;

__global__ __launch_bounds__(256) void hloss_main(
    const float* __restrict__ preds,
    const int*   __restrict__ targets,
    const float* __restrict__ cw,
    const float* __restrict__ pen,
    float4* __restrict__ partial,   // one float4 per block: {num, den, h, 0}
    int nquads)
{
    __shared__ float s_cw[NC];
    __shared__ float s_pen[NC * NC];
    if (threadIdx.x < NC * NC) s_pen[threadIdx.x] = pen[threadIdx.x];
    if (threadIdx.x < NC)      s_cw[threadIdx.x]  = cw[threadIdx.x];
    __syncthreads();

    float a_num = 0.f, a_den = 0.f, a_h = 0.f;

    const int stride = gridDim.x * blockDim.x;
    for (int q = blockIdx.x * blockDim.x + threadIdx.x; q < nquads; q += stride) {
        // 4 rows = 24 floats = 6 aligned float4 loads, issued back-to-back
        const float4* base = reinterpret_cast<const float4*>(preds) + (size_t)q * 6;
        float4 v0 = base[0];
        float4 v1 = base[1];
        float4 v2 = base[2];
        float4 v3 = base[3];
        float4 v4 = base[4];
        float4 v5 = base[5];
        int4 t4 = reinterpret_cast<const int4*>(targets)[q];

        float x[24] = { v0.x, v0.y, v0.z, v0.w,  v1.x, v1.y, v1.z, v1.w,
                        v2.x, v2.y, v2.z, v2.w,  v3.x, v3.y, v3.z, v3.w,
                        v4.x, v4.y, v4.z, v4.w,  v5.x, v5.y, v5.z, v5.w };

        #pragma unroll
        for (int r = 0; r < 4; ++r) {
            const float* xr = x + r * 6;          // r compile-time after unroll
            const int t = (r == 0) ? t4.x : (r == 1) ? t4.y : (r == 2) ? t4.z : t4.w;

            float m = xr[0];
            #pragma unroll
            for (int j = 1; j < NC; ++j) m = fmaxf(m, xr[j]);

            float e[NC], s = 0.f;
            #pragma unroll
            for (int j = 0; j < NC; ++j) { e[j] = __expf(xr[j] - m); s += e[j]; }
            const float inv = __frcp_rn(s);

            // x[t] via compile-time-j select chain (no runtime array index -> no scratch)
            float xt = xr[0];
            #pragma unroll
            for (int j = 1; j < NC; ++j) xt = (t == j) ? xr[j] : xt;

            const float w   = s_cw[t];
            const float nll = __logf(s) - (xt - m);
            a_num += w * nll;
            a_den += w;

            const float* pr = s_pen + t * NC;     // LDS gather, tiny
            float h = 0.f;
            #pragma unroll
            for (int j = 0; j < NC; ++j) h += (j != t) ? e[j] * pr[j] : 0.f;
            a_h += h * inv;
        }
    }

    // wave (64-lane) butterfly reduction
    #pragma unroll
    for (int off = 32; off > 0; off >>= 1) {
        a_num += __shfl_xor(a_num, off);
        a_den += __shfl_xor(a_den, off);
        a_h   += __shfl_xor(a_h,   off);
    }

    __shared__ float red[3][4];
    const int wave = threadIdx.x >> 6;
    const int lane = threadIdx.x & 63;
    if (lane == 0) { red[0][wave] = a_num; red[1][wave] = a_den; red[2][wave] = a_h; }
    __syncthreads();
    if (threadIdx.x == 0) {
        float n = 0.f, d = 0.f, h = 0.f;
        #pragma unroll
        for (int i = 0; i < 4; ++i) { n += red[0][i]; d += red[1][i]; h += red[2][i]; }
        partial[blockIdx.x] = make_float4(n, d, h, 0.f);   // contention-free store
    }
}

__global__ __launch_bounds__(256) void hloss_reduce(
    const float4* __restrict__ partial, int nblocks,
    float* __restrict__ out, float invB)
{
    float n = 0.f, d = 0.f, h = 0.f;
    for (int i = threadIdx.x; i < nblocks; i += 256) {
        float4 p = partial[i];
        n += p.x; d += p.y; h += p.z;
    }
    #pragma unroll
    for (int off = 32; off > 0; off >>= 1) {
        n += __shfl_xor(n, off);
        d += __shfl_xor(d, off);
        h += __shfl_xor(h, off);
    }
    __shared__ float red[3][4];
    const int wave = threadIdx.x >> 6;
    const int lane = threadIdx.x & 63;
    if (lane == 0) { red[0][wave] = n; red[1][wave] = d; red[2][wave] = h; }
    __syncthreads();
    if (threadIdx.x == 0) {
        float N = 0.f, D = 0.f, H = 0.f;
        #pragma unroll
        for (int i = 0; i < 4; ++i) { N += red[0][i]; D += red[1][i]; H += red[2][i]; }
        const float ce = N / D;
        const float hh = H * invB;
        out[0] = ce + HIER_W * hh;  // total_loss
        out[1] = ce;                // ce_loss
        out[2] = hh;                // hierarchy_loss
    }
}

extern "C" void kernel_launch(void* const* d_in, const int* in_sizes, int n_in,
                              void* d_out, int out_size, void* d_ws, size_t ws_size,
                              hipStream_t stream)
{
    const float* preds   = (const float*)d_in[0];
    const int*   targets = (const int*)  d_in[1];
    const float* cw      = (const float*)d_in[2];
    const float* pen     = (const float*)d_in[3];
    float4* partial = (float4*)d_ws;
    float* out = (float*)d_out;

    const int B = in_sizes[1];       // number of rows (targets count), 4194304
    const int nquads = B / 4;

    const int threads = 256;
    const int blocks = 2048;         // 8 blocks/CU; grid-stride covers the rest

    hipLaunchKernelGGL(hloss_main, dim3(blocks), dim3(threads), 0, stream,
                       preds, targets, cw, pen, partial, nquads);
    hipLaunchKernelGGL(hloss_reduce, dim3(1), dim3(threads), 0, stream,
                       partial, blocks, out, 1.0f / (float)B);
}